// Round 3
// baseline (1109.687 us; speedup 1.0000x reference)
//
#include <hip/hip_runtime.h>

#define NN 100000      // N_NODES
#define NE 1000000     // N_EDGES
#define HID 75
#define SP 80          // padded feature stride (fp32 h buffers)
#define OUTF 64
#define BN_EPS 1e-5f

#define SCAN_ELEMS 1024
#define SCAN_NBLK ((NN + SCAN_ELEMS - 1) / SCAN_ELEMS)   // 98

// bf16 helpers
__device__ __forceinline__ ushort f2bf(float f) {
    unsigned u = __float_as_uint(f);
    u += 0x7FFF + ((u >> 16) & 1);          // round-to-nearest-even
    return (ushort)(u >> 16);
}
__device__ __forceinline__ float bf_lo(unsigned u) { return __uint_as_float(u << 16); }
__device__ __forceinline__ float bf_hi(unsigned u) { return __uint_as_float(u & 0xFFFF0000u); }

// ---------------- CSR build ----------------
__global__ void hist_kernel(const int* __restrict__ dst, int* __restrict__ hist, int E) {
    int e = blockIdx.x * blockDim.x + threadIdx.x;
    if (e < E) atomicAdd(&hist[dst[e]], 1);
}

__global__ void dinv_kernel(const int* __restrict__ hist, float* __restrict__ dinv, int n) {
    int i = blockIdx.x * blockDim.x + threadIdx.x;
    if (i < n) dinv[i] = rsqrtf((float)hist[i] + 1.0f);   // +1 self-loop
}

__global__ void scan_pass1(const int* __restrict__ hist, int* __restrict__ bsum) {
    __shared__ int sdata[256];
    int base = blockIdx.x * SCAN_ELEMS;
    int t = threadIdx.x;
    int s = 0;
    #pragma unroll
    for (int k = 0; k < 4; ++k) {
        int i = base + t * 4 + k;
        if (i < NN) s += hist[i];
    }
    sdata[t] = s;
    __syncthreads();
    for (int off = 128; off > 0; off >>= 1) {
        if (t < off) sdata[t] += sdata[t + off];
        __syncthreads();
    }
    if (t == 0) bsum[blockIdx.x] = sdata[0];
}

__global__ void scan_pass2(int* __restrict__ bsum, int* __restrict__ row_ptr, int nblk) {
    if (threadIdx.x == 0) {
        int acc = 0;
        for (int i = 0; i < nblk; ++i) { int v = bsum[i]; bsum[i] = acc; acc += v; }
        row_ptr[NN] = acc;
    }
}

__global__ void scan_pass3(const int* __restrict__ hist, const int* __restrict__ bsum,
                           int* __restrict__ row_ptr) {
    __shared__ int sdata[256];
    int base = blockIdx.x * SCAN_ELEMS;
    int t = threadIdx.x;
    int v[4];
    int s = 0;
    #pragma unroll
    for (int k = 0; k < 4; ++k) {
        int i = base + t * 4 + k;
        v[k] = (i < NN) ? hist[i] : 0;
        s += v[k];
    }
    sdata[t] = s;
    __syncthreads();
    for (int off = 1; off < 256; off <<= 1) {
        int x = (t >= off) ? sdata[t - off] : 0;
        __syncthreads();
        sdata[t] += x;
        __syncthreads();
    }
    int pre = bsum[blockIdx.x] + sdata[t] - s;
    #pragma unroll
    for (int k = 0; k < 4; ++k) {
        int i = base + t * 4 + k;
        if (i < NN) { row_ptr[i] = pre; pre += v[k]; }
    }
}

__global__ void csr_fill(const int* __restrict__ src, const int* __restrict__ dst,
                         const int* __restrict__ row_ptr, int* __restrict__ cnt,
                         int* __restrict__ col, int E) {
    int e = blockIdx.x * blockDim.x + threadIdx.x;
    if (e >= E) return;
    int d = dst[e];
    int slot = row_ptr[d] + atomicAdd(&cnt[d], 1);
    col[slot] = src[e];
}

// ---------------- embedding gather ----------------
__global__ void embed_kernel(const int* __restrict__ x, const float* __restrict__ emb,
                             float* __restrict__ h) {
    int t = blockIdx.x * blockDim.x + threadIdx.x;
    if (t >= NN * SP) return;
    int node = t / SP, f = t % SP;
    h[t] = (f < HID) ? emb[x[node] * HID + f] : 0.0f;
}

// ---------------- GEMM: outb[n] = bf16( dinv[n] * (BNReLU(h[n]) @ W) ) ----------------
// h: fp32 stride SP. outb: bf16, stride 80 (J=75, pad zeroed) or 64 (J=64).
template<int J, bool BNRELU>
__global__ void gemm_kernel(const float* __restrict__ h, const float* __restrict__ W,
                            const float* __restrict__ ab, const float* __restrict__ dinv,
                            ushort* __restrict__ outb) {
    constexpr int CJ = (J + 3) / 4;   // 19 or 16
    constexpr int JP = CJ * 4;        // 76 or 64
    constexpr int NB = 256 / CJ;      // 13 or 16
    constexpr int KP = 76;            // padded K (rows 75 zeroed)
    __shared__ __align__(16) float Wlds[KP * JP];
    __shared__ __align__(16) float sA[SP];
    __shared__ __align__(16) float sC[SP];
    int tl = threadIdx.x;
    for (int idx = tl; idx < KP * JP; idx += 256) {
        int k = idx / JP, j = idx % JP;
        Wlds[idx] = (k < HID && j < J) ? W[k * J + j] : 0.0f;
    }
    if (BNRELU) {
        if (tl < SP) { sA[tl] = ab[tl]; sC[tl] = ab[SP + tl]; }
    }
    __syncthreads();
    int nn_local = tl / CJ;
    int c = tl % CJ;
    if (nn_local >= NB) return;
    int n = blockIdx.x * NB + nn_local;
    if (n >= NN) return;
    const float* hrow = h + (size_t)n * SP;
    float4 acc = make_float4(0.f, 0.f, 0.f, 0.f);
    #pragma unroll
    for (int k4 = 0; k4 < 19; ++k4) {
        float4 h4 = *reinterpret_cast<const float4*>(hrow + k4 * 4);
        if (BNRELU) {
            const float4 a4 = *reinterpret_cast<const float4*>(sA + k4 * 4);
            const float4 c4 = *reinterpret_cast<const float4*>(sC + k4 * 4);
            h4.x = fmaxf(fmaf(h4.x, a4.x, c4.x), 0.f);
            h4.y = fmaxf(fmaf(h4.y, a4.y, c4.y), 0.f);
            h4.z = fmaxf(fmaf(h4.z, a4.z, c4.z), 0.f);
            h4.w = fmaxf(fmaf(h4.w, a4.w, c4.w), 0.f);
        }
        const float* wr = &Wlds[(k4 * 4) * JP + c * 4];
        float4 w;
        w = *reinterpret_cast<const float4*>(wr);
        acc.x = fmaf(h4.x, w.x, acc.x); acc.y = fmaf(h4.x, w.y, acc.y);
        acc.z = fmaf(h4.x, w.z, acc.z); acc.w = fmaf(h4.x, w.w, acc.w);
        w = *reinterpret_cast<const float4*>(wr + JP);
        acc.x = fmaf(h4.y, w.x, acc.x); acc.y = fmaf(h4.y, w.y, acc.y);
        acc.z = fmaf(h4.y, w.z, acc.z); acc.w = fmaf(h4.y, w.w, acc.w);
        w = *reinterpret_cast<const float4*>(wr + 2 * JP);
        acc.x = fmaf(h4.z, w.x, acc.x); acc.y = fmaf(h4.z, w.y, acc.y);
        acc.z = fmaf(h4.z, w.z, acc.z); acc.w = fmaf(h4.z, w.w, acc.w);
        w = *reinterpret_cast<const float4*>(wr + 3 * JP);
        acc.x = fmaf(h4.w, w.x, acc.x); acc.y = fmaf(h4.w, w.y, acc.y);
        acc.z = fmaf(h4.w, w.z, acc.z); acc.w = fmaf(h4.w, w.w, acc.w);
    }
    float d = dinv[n];
    ushort4 o;
    o.x = f2bf(acc.x * d); o.y = f2bf(acc.y * d);
    o.z = f2bf(acc.z * d); o.w = f2bf(acc.w * d);
    constexpr int OS = (J == HID) ? 80 : 64;
    ushort* orow = outb + (size_t)n * OS;
    reinterpret_cast<ushort4*>(orow)[c] = o;
    if (J == HID && c == 0) {
        reinterpret_cast<ushort4*>(orow)[19] = make_ushort4(0, 0, 0, 0);  // feats 76..79
    }
}

// ---------------- CSR gather (bf16 in, fp32 out) ----------------
// gather75: block=320, grid=3125 (NN*10 threads exactly). Fused BN stats.
__global__ void gather75(const int* __restrict__ row_ptr, const int* __restrict__ col,
                         const uint4* __restrict__ hWb, const float* __restrict__ dinv,
                         float* __restrict__ agg, float* __restrict__ stats) {
    __shared__ float ssum[SP], ssq[SP];
    int tl = threadIdx.x;
    if (tl < SP) { ssum[tl] = 0.f; ssq[tl] = 0.f; }
    __syncthreads();
    int t = blockIdx.x * 320 + tl;
    int n = t / 10, c = t % 10;
    int beg = row_ptr[n], end = row_ptr[n + 1];
    uint4 v = hWb[(size_t)n * 10 + c];     // self term (pre-scaled by dinv[src])
    float a0 = bf_lo(v.x), a1 = bf_hi(v.x), a2 = bf_lo(v.y), a3 = bf_hi(v.y);
    float a4 = bf_lo(v.z), a5 = bf_hi(v.z), a6 = bf_lo(v.w), a7 = bf_hi(v.w);
    int e = beg;
    for (; e + 1 < end; e += 2) {
        int s0 = col[e], s1 = col[e + 1];
        uint4 w0 = hWb[(size_t)s0 * 10 + c];
        uint4 w1 = hWb[(size_t)s1 * 10 + c];
        a0 += bf_lo(w0.x); a1 += bf_hi(w0.x); a2 += bf_lo(w0.y); a3 += bf_hi(w0.y);
        a4 += bf_lo(w0.z); a5 += bf_hi(w0.z); a6 += bf_lo(w0.w); a7 += bf_hi(w0.w);
        a0 += bf_lo(w1.x); a1 += bf_hi(w1.x); a2 += bf_lo(w1.y); a3 += bf_hi(w1.y);
        a4 += bf_lo(w1.z); a5 += bf_hi(w1.z); a6 += bf_lo(w1.w); a7 += bf_hi(w1.w);
    }
    if (e < end) {
        uint4 w0 = hWb[(size_t)col[e] * 10 + c];
        a0 += bf_lo(w0.x); a1 += bf_hi(w0.x); a2 += bf_lo(w0.y); a3 += bf_hi(w0.y);
        a4 += bf_lo(w0.z); a5 += bf_hi(w0.z); a6 += bf_lo(w0.w); a7 += bf_hi(w0.w);
    }
    float d = dinv[n];
    a0 *= d; a1 *= d; a2 *= d; a3 *= d; a4 *= d; a5 *= d; a6 *= d; a7 *= d;
    float4* arow = reinterpret_cast<float4*>(agg + (size_t)n * SP + c * 8);
    arow[0] = make_float4(a0, a1, a2, a3);
    arow[1] = make_float4(a4, a5, a6, a7);
    int fb = c * 8;
    atomicAdd(&ssum[fb + 0], a0); atomicAdd(&ssq[fb + 0], a0 * a0);
    atomicAdd(&ssum[fb + 1], a1); atomicAdd(&ssq[fb + 1], a1 * a1);
    atomicAdd(&ssum[fb + 2], a2); atomicAdd(&ssq[fb + 2], a2 * a2);
    atomicAdd(&ssum[fb + 3], a3); atomicAdd(&ssq[fb + 3], a3 * a3);
    atomicAdd(&ssum[fb + 4], a4); atomicAdd(&ssq[fb + 4], a4 * a4);
    atomicAdd(&ssum[fb + 5], a5); atomicAdd(&ssq[fb + 5], a5 * a5);
    atomicAdd(&ssum[fb + 6], a6); atomicAdd(&ssq[fb + 6], a6 * a6);
    atomicAdd(&ssum[fb + 7], a7); atomicAdd(&ssq[fb + 7], a7 * a7);
    __syncthreads();
    if (tl < SP) {
        atomicAdd(&stats[tl], ssum[tl]);
        atomicAdd(&stats[SP + tl], ssq[tl]);
    }
}

// gather64: block=256, grid=3125 (NN*8 threads exactly). Adds bias.
__global__ void gather64(const int* __restrict__ row_ptr, const int* __restrict__ col,
                         const uint4* __restrict__ hWb, const float* __restrict__ dinv,
                         const float* __restrict__ bias, float* __restrict__ out) {
    int t = blockIdx.x * 256 + threadIdx.x;
    int n = t / 8, c = t % 8;
    int beg = row_ptr[n], end = row_ptr[n + 1];
    uint4 v = hWb[(size_t)n * 8 + c];
    float a0 = bf_lo(v.x), a1 = bf_hi(v.x), a2 = bf_lo(v.y), a3 = bf_hi(v.y);
    float a4 = bf_lo(v.z), a5 = bf_hi(v.z), a6 = bf_lo(v.w), a7 = bf_hi(v.w);
    int e = beg;
    for (; e + 1 < end; e += 2) {
        int s0 = col[e], s1 = col[e + 1];
        uint4 w0 = hWb[(size_t)s0 * 8 + c];
        uint4 w1 = hWb[(size_t)s1 * 8 + c];
        a0 += bf_lo(w0.x); a1 += bf_hi(w0.x); a2 += bf_lo(w0.y); a3 += bf_hi(w0.y);
        a4 += bf_lo(w0.z); a5 += bf_hi(w0.z); a6 += bf_lo(w0.w); a7 += bf_hi(w0.w);
        a0 += bf_lo(w1.x); a1 += bf_hi(w1.x); a2 += bf_lo(w1.y); a3 += bf_hi(w1.y);
        a4 += bf_lo(w1.z); a5 += bf_hi(w1.z); a6 += bf_lo(w1.w); a7 += bf_hi(w1.w);
    }
    if (e < end) {
        uint4 w0 = hWb[(size_t)col[e] * 8 + c];
        a0 += bf_lo(w0.x); a1 += bf_hi(w0.x); a2 += bf_lo(w0.y); a3 += bf_hi(w0.y);
        a4 += bf_lo(w0.z); a5 += bf_hi(w0.z); a6 += bf_lo(w0.w); a7 += bf_hi(w0.w);
    }
    float d = dinv[n];
    float4 b0 = *reinterpret_cast<const float4*>(bias + c * 8);
    float4 b1 = *reinterpret_cast<const float4*>(bias + c * 8 + 4);
    float4* orow = reinterpret_cast<float4*>(out + (size_t)n * OUTF + c * 8);
    orow[0] = make_float4(fmaf(a0, d, b0.x), fmaf(a1, d, b0.y), fmaf(a2, d, b0.z), fmaf(a3, d, b0.w));
    orow[1] = make_float4(fmaf(a4, d, b1.x), fmaf(a5, d, b1.y), fmaf(a6, d, b1.z), fmaf(a7, d, b1.w));
}

// ---------------- BN finalize: stats -> affine (a, c) ----------------
__global__ void bn_finalize(const float* __restrict__ stats, const float* __restrict__ gamma,
                            const float* __restrict__ beta, float* __restrict__ ab) {
    int f = threadIdx.x;
    if (f >= SP) return;
    float a = 0.f, cc = 0.f;
    if (f < HID) {
        float mu = stats[f] * (1.0f / NN);
        float var = stats[SP + f] * (1.0f / NN) - mu * mu;
        a = gamma[f] * rsqrtf(var + BN_EPS);
        cc = beta[f] - mu * a;
    }
    ab[f] = a;
    ab[SP + f] = cc;
}

// ---------------- host ----------------
extern "C" void kernel_launch(void* const* d_in, const int* in_sizes, int n_in,
                              void* d_out, int out_size, void* d_ws, size_t ws_size,
                              hipStream_t stream) {
    const int*   x      = (const int*)d_in[0];
    const int*   ei     = (const int*)d_in[1];
    const float* emb    = (const float*)d_in[2];
    const float* Ws     = (const float*)d_in[3];
    const float* gammas = (const float*)d_in[5];
    const float* betas  = (const float*)d_in[6];
    const float* W_mu   = (const float*)d_in[7];
    const float* b_mu   = (const float*)d_in[8];
    const float* W_ls   = (const float*)d_in[9];
    const float* b_ls   = (const float*)d_in[10];
    float* out = (float*)d_out;

    const int E = in_sizes[1] / 2;
    const int* src = ei;
    const int* dst = ei + E;

    char* ws = (char*)d_ws;
    float*  dinv    = (float*) (ws + 0);            // NN floats
    float*  stats   = (float*) (ws + 400000);       // 160 floats
    float*  ab      = (float*) (ws + 400640);       // 160 floats
    int*    hist    = (int*)   (ws + 401408);       // NN ints
    int*    row_ptr = (int*)   (ws + 801408);       // NN+1 ints
    int*    cnt     = (int*)   (ws + 1201536);      // NN ints
    int*    bsum    = (int*)   (ws + 1601536);      // SCAN_NBLK ints
    int*    col     = (int*)   (ws + 1602048);      // NE ints (4 MB)
    float*  hA      = (float*) (ws + 5602048);      // NN*SP fp32 (32 MB)
    ushort* hBb     = (ushort*)(ws + 37602048);     // NN*80 bf16 (16 MB)

    // --- CSR build ---
    hipMemsetAsync(hist, 0, NN * sizeof(int), stream);
    hist_kernel<<<(E + 255) / 256, 256, 0, stream>>>(dst, hist, E);
    dinv_kernel<<<(NN + 255) / 256, 256, 0, stream>>>(hist, dinv, NN);
    scan_pass1<<<SCAN_NBLK, 256, 0, stream>>>(hist, bsum);
    scan_pass2<<<1, 64, 0, stream>>>(bsum, row_ptr, SCAN_NBLK);
    scan_pass3<<<SCAN_NBLK, 256, 0, stream>>>(hist, bsum, row_ptr);
    hipMemsetAsync(cnt, 0, NN * sizeof(int), stream);
    csr_fill<<<(E + 255) / 256, 256, 0, stream>>>(src, dst, row_ptr, cnt, col, E);

    // --- h0 = emb[x] ---
    embed_kernel<<<(NN * SP + 255) / 256, 256, 0, stream>>>(x, emb, hA);

    // --- 4 GCN+BN+ReLU layers ---
    for (int layer = 0; layer < 4; ++layer) {
        const float* W = Ws + (size_t)layer * HID * HID;
        if (layer == 0)
            gemm_kernel<HID, false><<<(NN + 12) / 13, 256, 0, stream>>>(hA, W, ab, dinv, hBb);
        else
            gemm_kernel<HID, true><<<(NN + 12) / 13, 256, 0, stream>>>(hA, W, ab, dinv, hBb);
        hipMemsetAsync(stats, 0, 2 * SP * sizeof(float), stream);
        gather75<<<3125, 320, 0, stream>>>(row_ptr, col, (const uint4*)hBb, dinv, hA, stats);
        bn_finalize<<<1, 128, 0, stream>>>(stats, gammas + layer * HID, betas + layer * HID, ab);
    }

    // --- mu ---
    gemm_kernel<OUTF, true><<<(NN + 15) / 16, 256, 0, stream>>>(hA, W_mu, ab, dinv, hBb);
    gather64<<<3125, 256, 0, stream>>>(row_ptr, col, (const uint4*)hBb, dinv, b_mu, out);

    // --- logstd ---
    float* out2 = out + (size_t)NN * OUTF;
    gemm_kernel<OUTF, true><<<(NN + 15) / 16, 256, 0, stream>>>(hA, W_ls, ab, dinv, hBb);
    gather64<<<3125, 256, 0, stream>>>(row_ptr, col, (const uint4*)hBb, dinv, b_ls, out2);
}